// Round 5
// baseline (175.475 us; speedup 1.0000x reference)
//
#include <hip/hip_runtime.h>

// Cost-volume block: f1n = l2norm_C(f1); hori/verti 9-offset correlations vs f2,
// mean over C, leaky_relu(0.01), concat -> [B, 18, H, W].  B=256,C=64,H=W=64,sr=4.
//
// R5 = R2's register-staged single-barrier pipeline (loads issued right after a
// barrier, consumed before the next -> __syncthreads' vmcnt(0) drain costs ~0,
// COMP covers the latency) + R3's unpadded LDS rows with mask-multiplied
// horizontal edges + NO launch_bounds register cap (R2's failure was the
// VGPR=64 cap -> spills; R2's schedule itself was correct & passing).

constexpr int SR   = 4;
constexpr int NOFF = 2 * SR + 1;     // 9
constexpr int Bb   = 256;
constexpr int Cc   = 64;
constexpr int Hh   = 64;
constexpr int Ww   = 64;
constexpr int BH   = 16;             // h rows per block
constexpr int BAND = BH + 2 * SR;    // 24 staged f2 rows
constexpr int ROWF = Ww;             // 64 floats/row, unpadded (256 B)
constexpr int CCH  = 2;              // channels per chunk
constexpr int BUF_FLOATS = CCH * BAND * ROWF;   // 3072 floats = 12 KiB/buffer
constexpr int CH_STRIDE  = Hh * Ww;             // 4096
constexpr int CHUNK_STRIDE = CCH * CH_STRIDE;   // 8192

__device__ __forceinline__ float lrelu(float x) {
    return fmaxf(x, 0.01f * x);   // exact leaky relu, slope 0.01
}

__global__ __launch_bounds__(256)
void cv_kernel(const float* __restrict__ f1, const float* __restrict__ f2,
               float* __restrict__ out)
{
    __shared__ float lds[2 * BUF_FLOATS];   // 24 KiB

    const int t  = threadIdx.x;
    const int tx = t & 15;          // w-granule (4 floats)
    const int ty = t >> 4;          // h row within tile
    const int b  = blockIdx.x;
    const int h0 = blockIdx.y * BH;
    const int h  = h0 + ty;

    // ---- staging geometry: 3 float4 granules per thread per chunk ----
    const float* pk[3]; int ldsoff[3]; bool val[3];
#pragma unroll
    for (int k = 0; k < 3; ++k) {
        const int g   = t + 256 * k;          // [0, 768)
        const int c   = g / (BAND * 16);      // channel within chunk (0..1)
        const int rem = g - c * (BAND * 16);
        const int r   = rem >> 4;             // band row (0..23)
        const int gc  = rem & 15;             // w-granule
        const int row = h0 - SR + r;
        val[k]    = (row >= 0) && (row < Hh);
        pk[k]     = f2 + ((size_t)(b * Cc + c) * Hh + (val[k] ? row : 0)) * Ww + 4 * gc;
        ldsoff[k] = (c * BAND + r) * ROWF + 4 * gc;
    }
    const float* f1p = f1 + ((size_t)(b * Cc) * Hh + h) * Ww + 4 * tx;

    float hacc[NOFF][4], vacc[NOFF][4], nsq[4];
#pragma unroll
    for (int d = 0; d < NOFF; ++d)
#pragma unroll
        for (int q = 0; q < 4; ++q) { hacc[d][q] = 0.f; vacc[d][q] = 0.f; }
#pragma unroll
    for (int q = 0; q < 4; ++q) nsq[q] = 0.f;

    const float m0 = (tx == 0)  ? 0.f : 1.f;   // left-edge tap mask
    const float m1 = (tx == 15) ? 0.f : 1.f;   // right-edge tap mask

    float4 sv[3], fA[2], fB[2];

    auto GF2 = [&](int m) {                  // issue f2 chunk m -> sv regs
#pragma unroll
        for (int k = 0; k < 3; ++k)
            sv[k] = val[k] ? *reinterpret_cast<const float4*>(pk[k] + (size_t)m * CHUNK_STRIDE)
                           : make_float4(0.f, 0.f, 0.f, 0.f);
    };
    auto WR = [&](int bu) {                  // sv regs -> LDS buffer bu
#pragma unroll
        for (int k = 0; k < 3; ++k)
            *reinterpret_cast<float4*>(&lds[bu * BUF_FLOATS + ldsoff[k]]) = sv[k];
    };
    auto GF1 = [&](float4* F, int m) {       // f1 chunk m -> F[0..1]
        F[0] = *reinterpret_cast<const float4*>(f1p + (size_t)m * CHUNK_STRIDE);
        F[1] = *reinterpret_cast<const float4*>(f1p + (size_t)m * CHUNK_STRIDE + CH_STRIDE);
    };
    auto COMP = [&](int bu, const float4* F) {
        const float* Lb = &lds[bu * BUF_FLOATS];
#pragma unroll
        for (int c = 0; c < CCH; ++c) {
            const float4 av = F[c];
            nsq[0] += av.x * av.x; nsq[1] += av.y * av.y;
            nsq[2] += av.z * av.z; nsq[3] += av.w * av.w;

            const float* rp = Lb + (c * BAND + ty + SR) * ROWF + 4 * tx;
            float win[12];
            *reinterpret_cast<float4*>(&win[0]) = *reinterpret_cast<const float4*>(rp - 4);
            *reinterpret_cast<float4*>(&win[4]) = *reinterpret_cast<const float4*>(rp);
            *reinterpret_cast<float4*>(&win[8]) = *reinterpret_cast<const float4*>(rp + 4);
            win[0] *= m0; win[1] *= m0; win[2]  *= m0; win[3]  *= m0;
            win[8] *= m1; win[9] *= m1; win[10] *= m1; win[11] *= m1;
#pragma unroll
            for (int d = 0; d < NOFF; ++d) {
                hacc[d][0] += av.x * win[d];
                hacc[d][1] += av.y * win[d + 1];
                hacc[d][2] += av.z * win[d + 2];
                hacc[d][3] += av.w * win[d + 3];
            }
#pragma unroll
            for (int d = 0; d < NOFF; ++d) {
                const float4 v = *reinterpret_cast<const float4*>(
                    Lb + (c * BAND + ty + d) * ROWF + 4 * tx);
                vacc[d][0] += av.x * v.x; vacc[d][1] += av.y * v.y;
                vacc[d][2] += av.z * v.z; vacc[d][3] += av.w * v.w;
            }
        }
    };

    // ---- pipeline: 1 barrier per chunk; loads never cross a barrier ----
    GF2(0); GF1(fA, 0);
    WR(0);
    __syncthreads();
    GF2(1); GF1(fB, 1);

#pragma unroll 1
    for (int it = 0; it < 15; ++it) {
        const int m = 2 * it;
        COMP(0, fA);            // chunk m (covers the chunk m+1 loads in flight)
        WR(1);                  // sv = chunk m+1 -> buf1
        __syncthreads();
        GF2(m + 2); GF1(fA, m + 2);
        COMP(1, fB);            // chunk m+1 (covers chunk m+2 loads)
        WR(0);                  // chunk m+2 -> buf0
        __syncthreads();
        GF2(m + 3); GF1(fB, m + 3);
    }
    // state: buf0 = chunk 30, fA = f1 chunk 30, sv/fB = chunk 31 (in flight)
    COMP(0, fA);                // chunk 30
    WR(1);
    __syncthreads();
    COMP(1, fB);                // chunk 31

    // ---- epilogue: scale by 1/(C * max(||f1||, eps)), leaky relu, store ----
    float sc[4];
#pragma unroll
    for (int q = 0; q < 4; ++q)
        sc[q] = 1.0f / (64.0f * fmaxf(sqrtf(nsq[q]), 1e-12f));

    float* op = out + ((size_t)(b * 2 * NOFF) * Hh + h) * Ww + 4 * tx;
#pragma unroll
    for (int d = 0; d < NOFF; ++d) {
        float4 o;
        o.x = lrelu(hacc[d][0] * sc[0]);
        o.y = lrelu(hacc[d][1] * sc[1]);
        o.z = lrelu(hacc[d][2] * sc[2]);
        o.w = lrelu(hacc[d][3] * sc[3]);
        *reinterpret_cast<float4*>(op + (size_t)d * Hh * Ww) = o;
    }
#pragma unroll
    for (int d = 0; d < NOFF; ++d) {
        float4 o;
        o.x = lrelu(vacc[d][0] * sc[0]);
        o.y = lrelu(vacc[d][1] * sc[1]);
        o.z = lrelu(vacc[d][2] * sc[2]);
        o.w = lrelu(vacc[d][3] * sc[3]);
        *reinterpret_cast<float4*>(op + (size_t)(NOFF + d) * Hh * Ww) = o;
    }
}

extern "C" void kernel_launch(void* const* d_in, const int* in_sizes, int n_in,
                              void* d_out, int out_size, void* d_ws, size_t ws_size,
                              hipStream_t stream) {
    const float* f1 = (const float*)d_in[0];
    const float* f2 = (const float*)d_in[1];
    float* out = (float*)d_out;
    dim3 grid(Bb, Hh / BH);   // 256 x 4 = 1024 blocks
    cv_kernel<<<grid, dim3(256), 0, stream>>>(f1, f2, out);
}

// Round 7
// 152.575 us; speedup vs baseline: 1.1501x; 1.1501x over previous
//
#include <hip/hip_runtime.h>

// Cost-volume block: f1n = l2norm_C(f1); hori/verti 9-offset correlations vs f2,
// mean over C, leaky_relu(0.01), concat -> [B, 18, H, W].  B=256,C=64,H=W=64,sr=4.
//
// R7: 1-wave workgroups (no s_barrier, no vmcnt drains; 4096 independent waves).
// Cross-lane LDS RAW/WAR ordered by an lgkmcnt(0)+memory-clobber fence after
// each LDS write phase (R6 lacked this -> race). Horizontal window from LDS
// (+-1 granule, mask-multiplied edges — the R3/R5-proven numerics); center
// granule and the d=4 vertical tap come from the staging register. hacc[4] and
// vacc[4] are the same zero-offset dot -> computed once (saves 4 VGPR).

constexpr int SR   = 4;
constexpr int NOFF = 2 * SR + 1;   // 9
constexpr int Cc   = 64;
constexpr int Hh   = 64;
constexpr int Ww   = 64;
constexpr int BH   = 4;            // h rows per (1-wave) block
constexpr int BAND = BH + 2 * SR;  // 12 staged f2 rows
constexpr int CH   = Hh * Ww;      // 4096 floats per channel plane

__device__ __forceinline__ float lrelu(float x) {
    return fmaxf(x, 0.01f * x);
}

__global__ __launch_bounds__(64)
void cv_kernel(const float* __restrict__ f1, const float* __restrict__ f2,
               float* __restrict__ out)
{
    __shared__ float lds[2][BAND][Ww];   // 6 KiB, private to this single wave

    const int t  = threadIdx.x;
    const int tx = t & 15;          // w-granule (4 floats)
    const int ty = t >> 4;          // h row within tile (0..3)

    // XCD-chunked swizzle: each XCD gets a contiguous run of 512 blocks
    // (all 16 h-tiles of 32 consecutive b's) -> band halo re-reads hit L2.
    const int wg  = blockIdx.x;                 // 0..4095
    const int nid = (wg & 7) * 512 + (wg >> 3);
    const int b   = nid >> 4;
    const int h0  = (nid & 15) * BH;
    const int h   = h0 + ty;
    const bool top = (h0 == 0), bot = (h0 == Hh - BH);

    // Zero halo rows that are never staged (stay zero across all chunks).
    {
        const float4 z4 = make_float4(0.f, 0.f, 0.f, 0.f);
        if (top) {
            *reinterpret_cast<float4*>(&lds[0][ty][4 * tx]) = z4;
            *reinterpret_cast<float4*>(&lds[1][ty][4 * tx]) = z4;
        }
        if (bot) {
            *reinterpret_cast<float4*>(&lds[0][8 + ty][4 * tx]) = z4;
            *reinterpret_cast<float4*>(&lds[1][8 + ty][4 * tx]) = z4;
        }
    }

    float hacc[NOFF][4], vacc[NOFF][4], cacc[4], nsq[4];
#pragma unroll
    for (int d = 0; d < NOFF; ++d)
#pragma unroll
        for (int q = 0; q < 4; ++q) { hacc[d][q] = 0.f; vacc[d][q] = 0.f; }
#pragma unroll
    for (int q = 0; q < 4; ++q) { cacc[q] = 0.f; nsq[q] = 0.f; }

    // Per-thread staging rows: band rows {ty, ty+4, ty+8} at col granule tx.
    const float* g0 = f2 + (((size_t)b * Cc) * Hh + (h0 - SR + ty)) * Ww + 4 * tx;
    const float* g1 = f2 + (((size_t)b * Cc) * Hh + h) * Ww + 4 * tx;
    const float* g2 = f2 + (((size_t)b * Cc) * Hh + (h0 + SR + ty)) * Ww + 4 * tx;
    const float* ap = f1 + (((size_t)b * Cc) * Hh + h) * Ww + 4 * tx;

    const float m0 = (tx == 0)  ? 0.f : 1.f;   // left-edge tap mask
    const float m1 = (tx == 15) ? 0.f : 1.f;   // right-edge tap mask

    float4 A0, B0, C0, F0, A1, B1, C1, F1;     // two staging sets, static names

#define FENCE() asm volatile("s_waitcnt lgkmcnt(0)" ::: "memory")

#define LOADS(Ag, Bg, Cg, Fg, m)                                                \
    do {                                                                        \
        if (!top) Ag = *reinterpret_cast<const float4*>(g0 + (size_t)(m) * CH); \
        Bg = *reinterpret_cast<const float4*>(g1 + (size_t)(m) * CH);           \
        if (!bot) Cg = *reinterpret_cast<const float4*>(g2 + (size_t)(m) * CH); \
        Fg = *reinterpret_cast<const float4*>(ap + (size_t)(m) * CH);           \
    } while (0)

#define WR(bu, Ag, Bg, Cg)                                                    \
    do {                                                                      \
        if (!top) *reinterpret_cast<float4*>(&lds[bu][ty][4 * tx]) = Ag;      \
        *reinterpret_cast<float4*>(&lds[bu][4 + ty][4 * tx]) = Bg;            \
        if (!bot) *reinterpret_cast<float4*>(&lds[bu][8 + ty][4 * tx]) = Cg;  \
    } while (0)

#define COMP(bu, Bg, Fg)                                                      \
    do {                                                                      \
        const float4 av = Fg;                                                 \
        nsq[0] += av.x * av.x; nsq[1] += av.y * av.y;                         \
        nsq[2] += av.z * av.z; nsq[3] += av.w * av.w;                         \
        cacc[0] += av.x * Bg.x; cacc[1] += av.y * Bg.y;                       \
        cacc[2] += av.z * Bg.z; cacc[3] += av.w * Bg.w;                       \
        const float* rp = &lds[bu][4 + ty][4 * tx];                           \
        float4 wl = *reinterpret_cast<const float4*>(rp - 4);                 \
        float4 wr = *reinterpret_cast<const float4*>(rp + 4);                 \
        float win[12];                                                        \
        win[0] = wl.x * m0; win[1] = wl.y * m0;                               \
        win[2] = wl.z * m0; win[3] = wl.w * m0;                               \
        win[4] = Bg.x; win[5] = Bg.y; win[6] = Bg.z; win[7] = Bg.w;           \
        win[8] = wr.x * m1; win[9] = wr.y * m1;                               \
        win[10] = wr.z * m1; win[11] = wr.w * m1;                             \
        _Pragma("unroll")                                                     \
        for (int d = 0; d < NOFF; ++d) {                                      \
            if (d == SR) continue;                                            \
            hacc[d][0] += av.x * win[d];                                      \
            hacc[d][1] += av.y * win[d + 1];                                  \
            hacc[d][2] += av.z * win[d + 2];                                  \
            hacc[d][3] += av.w * win[d + 3];                                  \
        }                                                                     \
        _Pragma("unroll")                                                     \
        for (int d = 0; d < NOFF; ++d) {                                      \
            if (d == SR) continue;                                            \
            const float4 v = *reinterpret_cast<const float4*>(                \
                &lds[bu][ty + d][4 * tx]);                                    \
            vacc[d][0] += av.x * v.x; vacc[d][1] += av.y * v.y;               \
            vacc[d][2] += av.z * v.z; vacc[d][3] += av.w * v.w;               \
        }                                                                     \
    } while (0)

    // ---- pipeline: no barriers; fences order LDS only (vmem stays in flight)
    LOADS(A0, B0, C0, F0, 0);
    WR(0, A0, B0, C0);
    FENCE();

#pragma unroll 1
    for (int it = 0; it < 31; ++it) {
        const int m = 2 * it;
        LOADS(A1, B1, C1, F1, m + 1);
        COMP(0, B0, F0);            // chunk m
        WR(1, A1, B1, C1);
        FENCE();
        LOADS(A0, B0, C0, F0, m + 2);
        COMP(1, B1, F1);            // chunk m+1
        WR(0, A0, B0, C0);
        FENCE();
    }
    LOADS(A1, B1, C1, F1, 63);
    COMP(0, B0, F0);                // chunk 62
    WR(1, A1, B1, C1);
    FENCE();
    COMP(1, B1, F1);                // chunk 63

#undef LOADS
#undef WR
#undef COMP
#undef FENCE

    // ---- epilogue: scale by 1/(C * max(||f1||, eps)), leaky relu, store ----
    float sc[4];
#pragma unroll
    for (int q = 0; q < 4; ++q)
        sc[q] = 1.0f / (64.0f * fmaxf(sqrtf(nsq[q]), 1e-12f));

    float* op = out + (((size_t)b * 2 * NOFF) * Hh + h) * Ww + 4 * tx;
#pragma unroll
    for (int d = 0; d < NOFF; ++d) {
        const float* acc = (d == SR) ? cacc : hacc[d];
        float4 o;
        o.x = lrelu(acc[0] * sc[0]);
        o.y = lrelu(acc[1] * sc[1]);
        o.z = lrelu(acc[2] * sc[2]);
        o.w = lrelu(acc[3] * sc[3]);
        *reinterpret_cast<float4*>(op + (size_t)d * CH) = o;
    }
#pragma unroll
    for (int d = 0; d < NOFF; ++d) {
        const float* acc = (d == SR) ? cacc : vacc[d];
        float4 o;
        o.x = lrelu(acc[0] * sc[0]);
        o.y = lrelu(acc[1] * sc[1]);
        o.z = lrelu(acc[2] * sc[2]);
        o.w = lrelu(acc[3] * sc[3]);
        *reinterpret_cast<float4*>(op + (size_t)(NOFF + d) * CH) = o;
    }
}

extern "C" void kernel_launch(void* const* d_in, const int* in_sizes, int n_in,
                              void* d_out, int out_size, void* d_ws, size_t ws_size,
                              hipStream_t stream) {
    const float* f1 = (const float*)d_in[0];
    const float* f2 = (const float*)d_in[1];
    float* out = (float*)d_out;
    cv_kernel<<<dim3(256 * (Hh / BH)), dim3(64), 0, stream>>>(f1, f2, out);
}

// Round 8
// 143.730 us; speedup vs baseline: 1.2209x; 1.0615x over previous
//
#include <hip/hip_runtime.h>

// Cost-volume block: f1n = l2norm_C(f1); hori/verti 9-offset correlations vs f2,
// mean over C, leaky_relu(0.01), concat -> [B, 18, H, W].  B=256,C=64,H=W=64,sr=4.
//
// R8 = R7's barrier-free wave program, but 4 INDEPENDENT waves per workgroup
// (private 6 KiB LDS slice each, no cross-wave communication). R7's 1-wave WGs
// hit the per-CU workgroup-slot limit (~8 WGs -> occupancy 21%); packing 4
// waves/WG restores 16 waves/CU within 4 WG slots. The 4 waves cover 4
// adjacent h-tiles of one b, so their f2 bands overlap 8/12 rows (L1/L2 hits).

constexpr int SR   = 4;
constexpr int NOFF = 2 * SR + 1;   // 9
constexpr int Cc   = 64;
constexpr int Hh   = 64;
constexpr int Ww   = 64;
constexpr int BH   = 4;            // h rows per wave
constexpr int BAND = BH + 2 * SR;  // 12 staged f2 rows
constexpr int CH   = Hh * Ww;      // 4096 floats per channel plane

__device__ __forceinline__ float lrelu(float x) {
    return fmaxf(x, 0.01f * x);
}

__global__ __launch_bounds__(256)
void cv_kernel(const float* __restrict__ f1, const float* __restrict__ f2,
               float* __restrict__ out)
{
    __shared__ float lds[4][2][BAND][Ww];   // 24 KiB; [wave][buf][row][col]

    const int t    = threadIdx.x;
    const int lane = t & 63;
    const int wv   = t >> 6;        // wave id 0..3 (independent work unit)
    const int tx   = lane & 15;     // w-granule (4 floats)
    const int ty   = lane >> 4;     // h row within tile (0..3)

    // XCD-chunked swizzle over 1024 WGs: each XCD gets a contiguous run of
    // 128 WGs = all 4 tile-groups of 32 consecutive b's.
    const int wg  = blockIdx.x;                 // 0..1023
    const int nid = (wg & 7) * 128 + (wg >> 3);
    const int b   = nid >> 2;                   // 0..255
    const int h0  = ((nid & 3) * 4 + wv) * BH;  // this wave's h-tile origin
    const int h   = h0 + ty;
    const bool top = (h0 == 0), bot = (h0 == Hh - BH);

    // Zero halo rows that are never staged (stay zero across all chunks).
    {
        const float4 z4 = make_float4(0.f, 0.f, 0.f, 0.f);
        if (top) {
            *reinterpret_cast<float4*>(&lds[wv][0][ty][4 * tx]) = z4;
            *reinterpret_cast<float4*>(&lds[wv][1][ty][4 * tx]) = z4;
        }
        if (bot) {
            *reinterpret_cast<float4*>(&lds[wv][0][8 + ty][4 * tx]) = z4;
            *reinterpret_cast<float4*>(&lds[wv][1][8 + ty][4 * tx]) = z4;
        }
    }

    float hacc[NOFF][4], vacc[NOFF][4], cacc[4], nsq[4];
#pragma unroll
    for (int d = 0; d < NOFF; ++d)
#pragma unroll
        for (int q = 0; q < 4; ++q) { hacc[d][q] = 0.f; vacc[d][q] = 0.f; }
#pragma unroll
    for (int q = 0; q < 4; ++q) { cacc[q] = 0.f; nsq[q] = 0.f; }

    // Per-thread staging rows: band rows {ty, ty+4, ty+8} at col granule tx.
    const float* g0 = f2 + (((size_t)b * Cc) * Hh + (h0 - SR + ty)) * Ww + 4 * tx;
    const float* g1 = f2 + (((size_t)b * Cc) * Hh + h) * Ww + 4 * tx;
    const float* g2 = f2 + (((size_t)b * Cc) * Hh + (h0 + SR + ty)) * Ww + 4 * tx;
    const float* ap = f1 + (((size_t)b * Cc) * Hh + h) * Ww + 4 * tx;

    const float m0 = (tx == 0)  ? 0.f : 1.f;   // left-edge tap mask
    const float m1 = (tx == 15) ? 0.f : 1.f;   // right-edge tap mask

    float4 A0, B0, C0, F0, A1, B1, C1, F1;     // two staging sets, static names

#define FENCE() asm volatile("s_waitcnt lgkmcnt(0)" ::: "memory")

#define LOADS(Ag, Bg, Cg, Fg, m)                                                \
    do {                                                                        \
        if (!top) Ag = *reinterpret_cast<const float4*>(g0 + (size_t)(m) * CH); \
        Bg = *reinterpret_cast<const float4*>(g1 + (size_t)(m) * CH);           \
        if (!bot) Cg = *reinterpret_cast<const float4*>(g2 + (size_t)(m) * CH); \
        Fg = *reinterpret_cast<const float4*>(ap + (size_t)(m) * CH);           \
    } while (0)

#define WR(bu, Ag, Bg, Cg)                                                        \
    do {                                                                          \
        if (!top) *reinterpret_cast<float4*>(&lds[wv][bu][ty][4 * tx]) = Ag;      \
        *reinterpret_cast<float4*>(&lds[wv][bu][4 + ty][4 * tx]) = Bg;            \
        if (!bot) *reinterpret_cast<float4*>(&lds[wv][bu][8 + ty][4 * tx]) = Cg;  \
    } while (0)

#define COMP(bu, Bg, Fg)                                                      \
    do {                                                                      \
        const float4 av = Fg;                                                 \
        nsq[0] += av.x * av.x; nsq[1] += av.y * av.y;                         \
        nsq[2] += av.z * av.z; nsq[3] += av.w * av.w;                         \
        cacc[0] += av.x * Bg.x; cacc[1] += av.y * Bg.y;                       \
        cacc[2] += av.z * Bg.z; cacc[3] += av.w * Bg.w;                       \
        const float* rp = &lds[wv][bu][4 + ty][4 * tx];                       \
        float4 wl = *reinterpret_cast<const float4*>(rp - 4);                 \
        float4 wr = *reinterpret_cast<const float4*>(rp + 4);                 \
        float win[12];                                                        \
        win[0] = wl.x * m0; win[1] = wl.y * m0;                               \
        win[2] = wl.z * m0; win[3] = wl.w * m0;                               \
        win[4] = Bg.x; win[5] = Bg.y; win[6] = Bg.z; win[7] = Bg.w;           \
        win[8] = wr.x * m1; win[9] = wr.y * m1;                               \
        win[10] = wr.z * m1; win[11] = wr.w * m1;                             \
        _Pragma("unroll")                                                     \
        for (int d = 0; d < NOFF; ++d) {                                      \
            if (d == SR) continue;                                            \
            hacc[d][0] += av.x * win[d];                                      \
            hacc[d][1] += av.y * win[d + 1];                                  \
            hacc[d][2] += av.z * win[d + 2];                                  \
            hacc[d][3] += av.w * win[d + 3];                                  \
        }                                                                     \
        _Pragma("unroll")                                                     \
        for (int d = 0; d < NOFF; ++d) {                                      \
            if (d == SR) continue;                                            \
            const float4 v = *reinterpret_cast<const float4*>(                \
                &lds[wv][bu][ty + d][4 * tx]);                                \
            vacc[d][0] += av.x * v.x; vacc[d][1] += av.y * v.y;               \
            vacc[d][2] += av.z * v.z; vacc[d][3] += av.w * v.w;               \
        }                                                                     \
    } while (0)

    // ---- pipeline: no barriers; fences order LDS only (vmem stays in flight)
    LOADS(A0, B0, C0, F0, 0);
    WR(0, A0, B0, C0);
    FENCE();

#pragma unroll 1
    for (int it = 0; it < 31; ++it) {
        const int m = 2 * it;
        LOADS(A1, B1, C1, F1, m + 1);
        COMP(0, B0, F0);            // chunk m
        WR(1, A1, B1, C1);
        FENCE();
        LOADS(A0, B0, C0, F0, m + 2);
        COMP(1, B1, F1);            // chunk m+1
        WR(0, A0, B0, C0);
        FENCE();
    }
    LOADS(A1, B1, C1, F1, 63);
    COMP(0, B0, F0);                // chunk 62
    WR(1, A1, B1, C1);
    FENCE();
    COMP(1, B1, F1);                // chunk 63

#undef LOADS
#undef WR
#undef COMP
#undef FENCE

    // ---- epilogue: scale by 1/(C * max(||f1||, eps)), leaky relu, store ----
    float sc[4];
#pragma unroll
    for (int q = 0; q < 4; ++q)
        sc[q] = 1.0f / (64.0f * fmaxf(sqrtf(nsq[q]), 1e-12f));

    float* op = out + (((size_t)b * 2 * NOFF) * Hh + h) * Ww + 4 * tx;
#pragma unroll
    for (int d = 0; d < NOFF; ++d) {
        const float* acc = (d == SR) ? cacc : hacc[d];
        float4 o;
        o.x = lrelu(acc[0] * sc[0]);
        o.y = lrelu(acc[1] * sc[1]);
        o.z = lrelu(acc[2] * sc[2]);
        o.w = lrelu(acc[3] * sc[3]);
        *reinterpret_cast<float4*>(op + (size_t)d * CH) = o;
    }
#pragma unroll
    for (int d = 0; d < NOFF; ++d) {
        const float* acc = (d == SR) ? cacc : vacc[d];
        float4 o;
        o.x = lrelu(acc[0] * sc[0]);
        o.y = lrelu(acc[1] * sc[1]);
        o.z = lrelu(acc[2] * sc[2]);
        o.w = lrelu(acc[3] * sc[3]);
        *reinterpret_cast<float4*>(op + (size_t)(NOFF + d) * CH) = o;
    }
}

extern "C" void kernel_launch(void* const* d_in, const int* in_sizes, int n_in,
                              void* d_out, int out_size, void* d_ws, size_t ws_size,
                              hipStream_t stream) {
    const float* f1 = (const float*)d_in[0];
    const float* f2 = (const float*)d_in[1];
    float* out = (float*)d_out;
    cv_kernel<<<dim3(1024), dim3(256), 0, stream>>>(f1, f2, out);
}

// Round 9
// 128.611 us; speedup vs baseline: 1.3644x; 1.1176x over previous
//
#include <hip/hip_runtime.h>

// Cost-volume block: f1n = l2norm_C(f1); hori/verti 9-offset correlations vs f2,
// mean over C, leaky_relu(0.01), concat -> [B, 18, H, W].  B=256,C=64,H=W=64,sr=4.
//
// R9: wave-private DEPTH-3 counted-vmcnt pipeline. f2 staged by
// global_load_lds (no staging VGPRs), 3 LDS buffers per wave. Per phase:
// lgkmcnt(0) WAR fence -> issue stage(m+2)+f1(m+2) -> s_waitcnt vmcnt(8)
// (2 newer chunks stay in flight; stage(m) landed) -> COMP(m). vmcnt is
// per-wave HW state and buffers are wave-private => no cross-wave races.
// Boundary tiles dump their OOB segment into a scrap row so every wave
// issues exactly 4 vm-ops per chunk (uniform counts).

constexpr int SR   = 4;
constexpr int NOFF = 2 * SR + 1;   // 9
constexpr int Cc   = 64;
constexpr int Hh   = 64;
constexpr int Ww   = 64;
constexpr int BH   = 4;            // h rows per wave
constexpr int BAND = BH + 2 * SR;  // 12 staged f2 rows
constexpr int CH   = Hh * Ww;      // 4096 floats per channel plane
constexpr int BUFF = BAND * Ww;    // 768 floats per buffer

__device__ __forceinline__ float lrelu(float x) {
    return fmaxf(x, 0.01f * x);
}

__device__ __forceinline__ void gload16(const float* g, float* l) {
    __builtin_amdgcn_global_load_lds(
        (const __attribute__((address_space(1))) void*)g,
        (__attribute__((address_space(3))) void*)l, 16, 0, 0);
}

__global__ __launch_bounds__(256)
void cv_kernel(const float* __restrict__ f1, const float* __restrict__ f2,
               float* __restrict__ out)
{
    __shared__ float lds[4][3][BUFF];   // 36 KiB: [wave][buf][band row*64+col]
    __shared__ float dump[256];         // 1 KiB scrap for OOB segments

    const int t  = threadIdx.x;
    const int ln = t & 63;
    const int wv = t >> 6;          // wave id 0..3, independent work unit
    const int tx = ln & 15;         // w-granule (4 floats)
    const int ty = ln >> 4;         // h row within tile (0..3)

    // XCD-chunked swizzle: contiguous 128-WG runs per XCD (32 b's each).
    const int wg  = blockIdx.x;                 // 0..1023
    const int nid = (wg & 7) * 128 + (wg >> 3);
    const int b   = nid >> 2;
    const int h0  = ((nid & 3) * 4 + wv) * BH;  // this wave's h-tile origin
    const int h   = h0 + ty;
    const bool top = (h0 == 0), bot = (h0 == Hh - BH);

    float* Lw0 = &lds[wv][0][0];
    float* Lw1 = &lds[wv][1][0];
    float* Lw2 = &lds[wv][2][0];

    // Zero halo rows that are never staged (boundary waves dump instead),
    // once per buffer; they stay zero across all 64 chunks.
    {
        const float4 z4 = make_float4(0.f, 0.f, 0.f, 0.f);
        if (top) {
            *reinterpret_cast<float4*>(Lw0 + 4 * ln) = z4;
            *reinterpret_cast<float4*>(Lw1 + 4 * ln) = z4;
            *reinterpret_cast<float4*>(Lw2 + 4 * ln) = z4;
        }
        if (bot) {
            *reinterpret_cast<float4*>(Lw0 + 512 + 4 * ln) = z4;
            *reinterpret_cast<float4*>(Lw1 + 512 + 4 * ln) = z4;
            *reinterpret_cast<float4*>(Lw2 + 512 + 4 * ln) = z4;
        }
    }

    float hacc[NOFF][4], vacc[NOFF][4], cacc[4], nsq[4];
#pragma unroll
    for (int d = 0; d < NOFF; ++d)
#pragma unroll
        for (int q = 0; q < 4; ++q) { hacc[d][q] = 0.f; vacc[d][q] = 0.f; }
#pragma unroll
    for (int q = 0; q < 4; ++q) { cacc[q] = 0.f; nsq[q] = 0.f; }

    // Per-lane global sources for the 3 band segments (4 rows x 64 floats each).
    const int lc = 4 * tx;
    const float* fb  = f2 + (size_t)b * Cc * CH;
    const float* gs0 = fb + (size_t)(top ? ty : (h0 - 4 + ty)) * Ww + lc;
    const float* gs1 = fb + (size_t)(h0 + ty) * Ww + lc;
    const float* gs2 = fb + (size_t)(bot ? ty : (h0 + 4 + ty)) * Ww + lc;
    const float* f1p = f1 + (size_t)b * Cc * CH + (size_t)h * Ww + lc;

    const float m0 = (tx == 0)  ? 0.f : 1.f;   // left-edge tap mask
    const float m1 = (tx == 15) ? 0.f : 1.f;   // right-edge tap mask

    float4 F0, F1, F2;

#define FENL() do { asm volatile("s_waitcnt lgkmcnt(0)" ::: "memory"); } while (0)
#define FENV(N) do { asm volatile("s_waitcnt vmcnt(" #N ")" ::: "memory"); \
                     __builtin_amdgcn_sched_barrier(0); } while (0)

#define STAGE(LwX, off)                                   \
    do {                                                  \
        gload16(gs0 + (off), top ? dump : (LwX));         \
        gload16(gs1 + (off), (LwX) + 256);                \
        gload16(gs2 + (off), bot ? dump : (LwX) + 512);   \
    } while (0)

#define LDF(Fg, off) Fg = *reinterpret_cast<const float4*>(f1p + (off))

#define COMP(LwX, Fg)                                                         \
    do {                                                                      \
        const float4 av = Fg;                                                 \
        const float* rp = (LwX) + (4 + ty) * Ww + lc;                         \
        const float4 wl = *reinterpret_cast<const float4*>(rp - 4);           \
        const float4 cc = *reinterpret_cast<const float4*>(rp);               \
        const float4 wr = *reinterpret_cast<const float4*>(rp + 4);           \
        nsq[0] += av.x * av.x; nsq[1] += av.y * av.y;                         \
        nsq[2] += av.z * av.z; nsq[3] += av.w * av.w;                         \
        cacc[0] += av.x * cc.x; cacc[1] += av.y * cc.y;                       \
        cacc[2] += av.z * cc.z; cacc[3] += av.w * cc.w;                       \
        float win[12];                                                        \
        win[0] = wl.x * m0; win[1] = wl.y * m0;                               \
        win[2] = wl.z * m0; win[3] = wl.w * m0;                               \
        win[4] = cc.x; win[5] = cc.y; win[6] = cc.z; win[7] = cc.w;           \
        win[8] = wr.x * m1; win[9] = wr.y * m1;                               \
        win[10] = wr.z * m1; win[11] = wr.w * m1;                             \
        _Pragma("unroll")                                                     \
        for (int d = 0; d < NOFF; ++d) {                                      \
            if (d == SR) continue;                                            \
            hacc[d][0] += av.x * win[d];                                      \
            hacc[d][1] += av.y * win[d + 1];                                  \
            hacc[d][2] += av.z * win[d + 2];                                  \
            hacc[d][3] += av.w * win[d + 3];                                  \
        }                                                                     \
        _Pragma("unroll")                                                     \
        for (int d = 0; d < NOFF; ++d) {                                      \
            if (d == SR) continue;                                            \
            const float4 v = *reinterpret_cast<const float4*>(                \
                (LwX) + (ty + d) * Ww + lc);                                  \
            vacc[d][0] += av.x * v.x; vacc[d][1] += av.y * v.y;               \
            vacc[d][2] += av.z * v.z; vacc[d][3] += av.w * v.w;               \
        }                                                                     \
    } while (0)

    // ---- prologue: issue chunks 0,1 (8 vm-ops outstanding) ----
    STAGE(Lw0, 0); LDF(F0, 0);
    STAGE(Lw1, CH); LDF(F1, CH);

    // ---- main: 20 iters x 3 phases; phase m issues m+2, waits stage(m) ----
#pragma unroll 1
    for (int it = 0; it < 20; ++it) {
        const size_t base = (size_t)(3 * it) * CH;
        FENL(); STAGE(Lw2, base + 2 * CH); LDF(F2, base + 2 * CH);
        FENV(8); COMP(Lw0, F0);
        FENL(); STAGE(Lw0, base + 3 * CH); LDF(F0, base + 3 * CH);
        FENV(8); COMP(Lw1, F1);
        FENL(); STAGE(Lw1, base + 4 * CH); LDF(F1, base + 4 * CH);
        FENV(8); COMP(Lw2, F2);
    }
    // ---- tail: phases 60..63 ----
    FENL(); STAGE(Lw2, (size_t)62 * CH); LDF(F2, (size_t)62 * CH);
    FENV(8); COMP(Lw0, F0);
    FENL(); STAGE(Lw0, (size_t)63 * CH); LDF(F0, (size_t)63 * CH);
    FENV(8); COMP(Lw1, F1);
    FENL();
    FENV(4); COMP(Lw2, F2);
    FENV(0); COMP(Lw0, F0);

#undef FENL
#undef FENV
#undef STAGE
#undef LDF
#undef COMP

    // ---- epilogue: scale by 1/(C * max(||f1||, eps)), leaky relu, store ----
    float sc[4];
#pragma unroll
    for (int q = 0; q < 4; ++q)
        sc[q] = 1.0f / (64.0f * fmaxf(sqrtf(nsq[q]), 1e-12f));

    float* op = out + (((size_t)b * 2 * NOFF) * Hh + h) * Ww + lc;
#pragma unroll
    for (int d = 0; d < NOFF; ++d) {
        const float* acc = (d == SR) ? cacc : hacc[d];
        float4 o;
        o.x = lrelu(acc[0] * sc[0]);
        o.y = lrelu(acc[1] * sc[1]);
        o.z = lrelu(acc[2] * sc[2]);
        o.w = lrelu(acc[3] * sc[3]);
        *reinterpret_cast<float4*>(op + (size_t)d * CH) = o;
    }
#pragma unroll
    for (int d = 0; d < NOFF; ++d) {
        const float* acc = (d == SR) ? cacc : vacc[d];
        float4 o;
        o.x = lrelu(acc[0] * sc[0]);
        o.y = lrelu(acc[1] * sc[1]);
        o.z = lrelu(acc[2] * sc[2]);
        o.w = lrelu(acc[3] * sc[3]);
        *reinterpret_cast<float4*>(op + (size_t)(NOFF + d) * CH) = o;
    }
}

extern "C" void kernel_launch(void* const* d_in, const int* in_sizes, int n_in,
                              void* d_out, int out_size, void* d_ws, size_t ws_size,
                              hipStream_t stream) {
    const float* f1 = (const float*)d_in[0];
    const float* f2 = (const float*)d_in[1];
    float* out = (float*)d_out;
    cv_kernel<<<dim3(1024), dim3(256), 0, stream>>>(f1, f2, out);
}